// Round 12
// baseline (958.404 us; speedup 1.0000x reference)
//
#include <hip/hip_runtime.h>

#define T_LEN 1024
#define HID   32
#define LDIM  16
#define BATCH 512
#define NB    16
#define NT    512            // 8 waves
#define NGRP  32             // batch groups
#define CHUNK 16             // steps per sync chunk
#define NCHUNK (T_LEN / CHUNK)       // 64
#define RINGC 4                      // chunks in ring
#define RING_STEPS (CHUNK * RINGC)   // 64
#define SLOT_B 1024                  // bytes per step slot: 32u x 16n x f16
#define IFACE_B (RING_STEPS * SLOT_B)  // 64 KB per (layer-interface, group)
#define FLAGS_B 8192
#define ROWB  80
#define LOG2E 1.44269504f

typedef _Float16 half8 __attribute__((ext_vector_type(8)));
typedef float    f32x4 __attribute__((ext_vector_type(4)));
typedef unsigned u32;
typedef unsigned u32x4 __attribute__((ext_vector_type(4)));

#if defined(__has_builtin)
#if __has_builtin(__builtin_amdgcn_rcpf)
#define FAST_RCP(x) __builtin_amdgcn_rcpf(x)
#endif
#if __has_builtin(__builtin_amdgcn_exp2f)
#define FAST_EXP2(x) __builtin_amdgcn_exp2f(x)
#endif
#endif
#ifndef FAST_RCP
#define FAST_RCP(x) (1.0f / (x))
#endif
#ifndef FAST_EXP2
#define FAST_EXP2(x) __expf(0.69314718f * (x))
#endif

#define MFMA(a, b, c) __builtin_amdgcn_mfma_f32_16x16x32_f16((a), (b), (c), 0, 0, 0)

__device__ __forceinline__ u32 aloadA(u32* p) {
    return __hip_atomic_load(p, __ATOMIC_ACQUIRE, __HIP_MEMORY_SCOPE_AGENT);
}
__device__ __forceinline__ void astoreR(u32* p, u32 v) {
    __hip_atomic_store(p, v, __ATOMIC_RELEASE, __HIP_MEMORY_SCOPE_AGENT);
}
__device__ __forceinline__ void poll_ge(u32* p, int v) {
    if (v <= 0) return;
    while ((int)aloadA(p) < v) __builtin_amdgcn_s_sleep(2);
}

__global__ __launch_bounds__(NT, 1)
void lstm_encoder_kernel(const float* __restrict__ x,
                         const float* __restrict__ Wih0, const float* __restrict__ Whh0,
                         const float* __restrict__ bih0, const float* __restrict__ bhh0,
                         const float* __restrict__ Wih1, const float* __restrict__ Whh1,
                         const float* __restrict__ bih1, const float* __restrict__ bhh1,
                         const float* __restrict__ Wih2, const float* __restrict__ Whh2,
                         const float* __restrict__ bih2, const float* __restrict__ bhh2,
                         const float* __restrict__ Wm,  const float* __restrict__ bm,
                         const float* __restrict__ Wlv, const float* __restrict__ blv,
                         float* __restrict__ out, unsigned char* __restrict__ ws)
{
    const int bid  = blockIdx.x;
    const int g    = bid & (NGRP - 1);   // batch group
    const int l    = bid >> 5;           // layer 0..2
    const int b0   = g * NB;
    const int tid  = threadIdx.x;
    const int lane = tid & 63;
    const int wave = tid >> 6;           // 0..7
    const int n    = lane & 15;          // batch col / A-row index
    const int kc   = lane >> 4;          // k-chunk / D row-quad
    const int unit = 4 * wave + kc;      // this lane's owned unit

    // flags (64B-padded), then rings
    u32* pOut = (u32*)(ws + (size_t)(l * NGRP + g) * 64);                       // l<=1 publishes
    u32* pIn  = (u32*)(ws + (size_t)(((l > 0 ? l : 1) - 1) * NGRP + g) * 64);   // l>=1 consumes
    u32* cInA = (u32*)(ws + 4096 + (size_t)(((l > 0 ? l : 1) - 1) * NGRP + g) * 64); // my ack upstream
    u32* cOutA= (u32*)(ws + 4096 + (size_t)(l * NGRP + g) * 64);                // downstream ack to me
    unsigned char* ringAll = ws + FLAGS_B;
    unsigned char* ringIn  = ringAll + (size_t)(((l > 0 ? l : 1) - 1) * NGRP + g) * IFACE_B;
    unsigned char* ringOut = ringAll + (size_t)(l * NGRP + g) * IFACE_B;

    __shared__ __align__(16) unsigned char h_lds[2 * 16 * ROWB];     // own h, dbl-buffered
    __shared__ __align__(16) unsigned char pw[2 * CHUNK * SLOT_B];   // prev-layer chunk window
    __shared__ float cbuf[NB * HID];

    for (int i = tid; i < (int)(2 * 16 * ROWB / 4); i += NT) ((u32*)h_lds)[i] = 0u;

    // ---- A fragments + bias, exp2-prescaled ----
    // Tile-row m = 4*uloc + role (role 0..3 = i,f,g,o). A row = n; D reg r -> row 4kc+r
    // => lane(n,kc) gets all 4 gates of unit 4*wave+kc for batch n (1 full cell).
    const float* Wih = (l == 0) ? Wih0 : (l == 1) ? Wih1 : Wih2;
    const float* Whh = (l == 0) ? Whh0 : (l == 1) ? Whh1 : Whh2;
    const float* bih = (l == 0) ? bih0 : (l == 1) ? bih1 : bih2;
    const float* bhh = (l == 0) ? bhh0 : (l == 1) ? bhh1 : bhh2;

    half8 aself, aprev;
    f32x4 biasC;
    float wx0v[4], wx1v[4];
    {
        const int   Wrow = (n & 3) * 32 + 4 * wave + (n >> 2);
        const float scA  = ((n & 3) == 2) ? 2.0f * LOG2E : LOG2E;
#pragma unroll
        for (int i2 = 0; i2 < 8; ++i2) {
            const int kk = kc * 8 + i2;
            aself[i2] = (_Float16)(Whh[Wrow * HID + kk] * scA);
            aprev[i2] = (l == 0) ? (_Float16)0.0f
                                 : (_Float16)(Wih[Wrow * HID + kk] * scA);
        }
#pragma unroll
        for (int r = 0; r < 4; ++r) {
            const int   RD  = r * 32 + 4 * wave + kc;
            const float scD = (r == 2) ? 2.0f * LOG2E : LOG2E;
            biasC[r] = (bih[RD] + bhh[RD]) * scD;
            wx0v[r]  = (l == 0) ? Wih[RD * 2 + 0] * scD : 0.0f;
            wx1v[r]  = (l == 0) ? Wih[RD * 2 + 1] * scD : 0.0f;
        }
    }

    float cc = 0.0f;

    const float2* xb = (const float2*)x + (size_t)(b0 + n) * T_LEN;
    float2 xvn;
    if (l == 0) xvn = xb[0];

    // ---- consumer prologue: stage chunk0 into pw[0], issue chunk1 loads ----
    u32x4 st0 = {0, 0, 0, 0}, st1 = {0, 0, 0, 0};
    if (l > 0) {
        poll_ge(pIn, 1);
        st0 = *(const u32x4*)(ringIn + (size_t)(2 * wave) * SLOT_B + lane * 16);
        st1 = *(const u32x4*)(ringIn + (size_t)(2 * wave + 1) * SLOT_B + lane * 16);
        *(u32x4*)(pw + (2 * wave) * SLOT_B + lane * 16) = st0;
        *(u32x4*)(pw + (2 * wave + 1) * SLOT_B + lane * 16) = st1;
        __syncthreads();
        if (tid == 0) { __threadfence(); astoreR(cInA, 1u); }
        poll_ge(pIn, 2);
        st0 = *(const u32x4*)(ringIn + (size_t)(CHUNK + 2 * wave) * SLOT_B + lane * 16);
        st1 = *(const u32x4*)(ringIn + (size_t)(CHUNK + 2 * wave + 1) * SLOT_B + lane * 16);
    }
    __syncthreads();

    for (int t = 0; t < T_LEN; ++t) {
        const int P = t & 1;
        // own-h B-frag (h_l(t-1)); also IS the data the producer must ship (h(t-1))
        const u32x4 bf1r = *(const u32x4*)(h_lds + P * (16 * ROWB) + n * ROWB + kc * 16);
        if (l < 2 && wave == 0 && t > 0)
            *(u32x4*)(ringOut + (size_t)((t - 1) & (RING_STEPS - 1)) * SLOT_B + lane * 16) = bf1r;

        if ((t & (CHUNK - 1)) == 0 && t > 0) {
            const int c = t >> 4;
            asm volatile("s_waitcnt vmcnt(0)" ::: "memory");
            if (l < 2 && tid == 0) { __threadfence(); astoreR(pOut, (u32)c); }   // chunks 0..c-1 stored
            if (l > 0) {  // commit staged chunk c into its LDS buffer
                *(u32x4*)(pw + (c & 1) * (CHUNK * SLOT_B) + (2 * wave) * SLOT_B + lane * 16) = st0;
                *(u32x4*)(pw + (c & 1) * (CHUNK * SLOT_B) + (2 * wave + 1) * SLOT_B + lane * 16) = st1;
            }
            __syncthreads();
            if (l > 0) {
                if (tid == 0) { __threadfence(); astoreR(cInA, (u32)(c + 1)); }  // ring slots <=c free
                if (c + 1 < NCHUNK) {
                    poll_ge(pIn, c + 2);
                    const int rs = ((c + 1) * CHUNK) & (RING_STEPS - 1);
                    st0 = *(const u32x4*)(ringIn + (size_t)(rs + 2 * wave) * SLOT_B + lane * 16);
                    st1 = *(const u32x4*)(ringIn + (size_t)(rs + 2 * wave + 1) * SLOT_B + lane * 16);
                }
            }
            if (l < 2 && wave == 0) poll_ge(cOutA, c - (RINGC - 1));  // backpressure
        }

        f32x4 ac;
        if (l == 0) {
            const float2 xv = xvn;
            xvn = xb[(t + 1 < T_LEN) ? (t + 1) : (T_LEN - 1)];
#pragma unroll
            for (int r = 0; r < 4; ++r)
                ac[r] = fmaf(wx1v[r], xv.y, fmaf(wx0v[r], xv.x, biasC[r]));
        } else {
            const half8 bfP = __builtin_bit_cast(half8, *(const u32x4*)(
                pw + ((t >> 4) & 1) * (CHUNK * SLOT_B) + (t & (CHUNK - 1)) * SLOT_B + kc * 256 + n * 16));
            ac = MFMA(aprev, bfP, biasC);
        }
        ac = MFMA(aself, __builtin_bit_cast(half8, bf1r), ac);

        // CELL (1 per lane): ac = (i,f,g,o) pre-acts, exp2-prescaled
        const float ei  = FAST_EXP2(-ac[0]);
        const float ef  = FAST_EXP2(-ac[1]);
        const float eg  = FAST_EXP2(-ac[2]);
        const float eo  = FAST_EXP2(-ac[3]);
        const float p1  = (1.0f + ei) * (1.0f + eg);
        const float den = p1 * (1.0f + ef);
        const float tmn = (1.0f - eg) * (1.0f + ef);
        float c_ = fmaf(cc, p1, tmn) * FAST_RCP(den);
        c_ = fminf(fmaxf(c_, -20.0f), 20.0f);
        cc = c_;
        const float ec = FAST_EXP2(-2.0f * LOG2E * c_);
        const float hv = (1.0f - ec) * FAST_RCP((1.0f + eo) * (1.0f + ec));  // o*tanh(c)

        *(_Float16*)(h_lds + (P ^ 1) * (16 * ROWB) + n * ROWB + unit * 2) = (_Float16)hv;
        __syncthreads();
    }

    if (l < 2) {
        // ship h(1023) (sits in parity 0) and final publish
        const u32x4 bfF = *(const u32x4*)(h_lds + n * ROWB + kc * 16);
        if (wave == 0) {
            *(u32x4*)(ringOut + (size_t)((T_LEN - 1) & (RING_STEPS - 1)) * SLOT_B + lane * 16) = bfF;
            asm volatile("s_waitcnt vmcnt(0)" ::: "memory");
            if (lane == 0) { __threadfence(); astoreR(pOut, (u32)NCHUNK); }
        }
    } else {
        cbuf[n * HID + unit] = cc;
        __syncthreads();
        // projection: 512 threads = 16 batch x 2 outputs x 16 latent
        const int  nn = tid >> 5;
        const int  o  = tid & 31;
        const bool is_mean = (o < LDIM);
        const int  jo = o & (LDIM - 1);
        const float* W = is_mean ? Wm : Wlv;
        float acc = is_mean ? bm[jo] : blv[jo];
#pragma unroll
        for (int k = 0; k < HID; ++k) acc = fmaf(W[jo * HID + k], cbuf[nn * HID + k], acc);
        out[(is_mean ? 0 : (size_t)BATCH * LDIM) + (size_t)(b0 + nn) * LDIM + jo] = acc;
    }
}

extern "C" void kernel_launch(void* const* d_in, const int* in_sizes, int n_in,
                              void* d_out, int out_size, void* d_ws, size_t ws_size,
                              hipStream_t stream) {
    const float* x    = (const float*)d_in[0];
    const float* Wih0 = (const float*)d_in[1];
    const float* Whh0 = (const float*)d_in[2];
    const float* bih0 = (const float*)d_in[3];
    const float* bhh0 = (const float*)d_in[4];
    const float* Wih1 = (const float*)d_in[5];
    const float* Whh1 = (const float*)d_in[6];
    const float* bih1 = (const float*)d_in[7];
    const float* bhh1 = (const float*)d_in[8];
    const float* Wih2 = (const float*)d_in[9];
    const float* Whh2 = (const float*)d_in[10];
    const float* bih2 = (const float*)d_in[11];
    const float* bhh2 = (const float*)d_in[12];
    const float* Wm   = (const float*)d_in[13];
    const float* bm   = (const float*)d_in[14];
    const float* Wlv  = (const float*)d_in[15];
    const float* blv  = (const float*)d_in[16];
    float* out = (float*)d_out;

    // zero sync flags every launch (graph-capture safe; makes replays deterministic)
    hipMemsetAsync(d_ws, 0, FLAGS_B, stream);

    lstm_encoder_kernel<<<dim3(3 * NGRP), dim3(NT), 0, stream>>>(
        x, Wih0, Whh0, bih0, bhh0, Wih1, Whh1, bih1, bhh1,
        Wih2, Whh2, bih2, bhh2, Wm, bm, Wlv, blv, out,
        (unsigned char*)d_ws);
}

// Round 13
// 490.331 us; speedup vs baseline: 1.9546x; 1.9546x over previous
//
#include <hip/hip_runtime.h>

#define T_LEN 1024
#define HID   32
#define LDIM  16
#define BATCH 512
#define NB    16             // batch elems per block (MFMA N)
#define NT    768            // 12 waves: 3 layers x 4 unit-groups
#define ROWB  80             // bytes per n-row (64 data + 16 pad)
#define SLOTB (16 * ROWB)    // 16 n-rows = 1280 B
#define SLOT_ALL (4 * SLOTB) // {h0,h1,h2,x} per time-slot = 5120 B
#define NSLOT 8              // h ring depth (t mod 8)
#define LOG2E 1.44269504f

typedef _Float16 half8  __attribute__((ext_vector_type(8)));
typedef _Float16 half2v __attribute__((ext_vector_type(2)));
typedef float    f32x4  __attribute__((ext_vector_type(4)));
typedef unsigned u32;
typedef unsigned u32x4  __attribute__((ext_vector_type(4)));

#if defined(__has_builtin)
#if __has_builtin(__builtin_amdgcn_rcpf)
#define FAST_RCP(x) __builtin_amdgcn_rcpf(x)
#endif
#if __has_builtin(__builtin_amdgcn_exp2f)
#define FAST_EXP2(x) __builtin_amdgcn_exp2f(x)
#endif
#if __has_builtin(__builtin_amdgcn_cvt_pkrtz)
#define PKRTZ(a, b) __builtin_bit_cast(u32, __builtin_amdgcn_cvt_pkrtz((a), (b)))
#endif
#endif
#ifndef FAST_RCP
#define FAST_RCP(x) (1.0f / (x))
#endif
#ifndef FAST_EXP2
#define FAST_EXP2(x) __expf(0.69314718f * (x))
#endif
#ifndef PKRTZ
static __device__ __forceinline__ u32 pkrtz_fallback(float a, float b) {
    half2v v; v[0] = (_Float16)a; v[1] = (_Float16)b;
    return __builtin_bit_cast(u32, v);
}
#define PKRTZ(a, b) pkrtz_fallback((a), (b))
#endif

#define MFMA(a, b, c) __builtin_amdgcn_mfma_f32_16x16x32_f16((a), (b), (c), 0, 0, 0)

// acquire-load spin on an LDS counter (wave-uniform address & condition)
__device__ __forceinline__ void waitc(const u32* p, u32 need) {
    while (__hip_atomic_load(p, __ATOMIC_ACQUIRE, __HIP_MEMORY_SCOPE_WORKGROUP) < need)
        __builtin_amdgcn_s_sleep(1);
}

__global__ __launch_bounds__(NT, 1)
void lstm_encoder_kernel(const float* __restrict__ x,
                         const float* __restrict__ Wih0, const float* __restrict__ Whh0,
                         const float* __restrict__ bih0, const float* __restrict__ bhh0,
                         const float* __restrict__ Wih1, const float* __restrict__ Whh1,
                         const float* __restrict__ bih1, const float* __restrict__ bhh1,
                         const float* __restrict__ Wih2, const float* __restrict__ Whh2,
                         const float* __restrict__ bih2, const float* __restrict__ bhh2,
                         const float* __restrict__ Wm,  const float* __restrict__ bm,
                         const float* __restrict__ Wlv, const float* __restrict__ blv,
                         float* __restrict__ out)
{
    const int b0   = blockIdx.x * NB;
    const int tid  = threadIdx.x;
    const int lane = tid & 63;
    const int wave = tid >> 6;        // 0..11
    const int l    = wave >> 2;       // layer 0..2
    const int w    = wave & 3;        // unit-group: units 8w..8w+7
    const int n    = lane & 15;       // batch col / A row-within-tile
    const int kc   = lane >> 4;       // k-chunk / D row-quad

    __shared__ u32 xs[T_LEN * NB];                              // 64 KB packed f16 x [t][n]
    __shared__ __align__(16) unsigned char ring[NSLOT * SLOT_ALL];  // 40 KB h/x ring
    __shared__ u32 cnt[48];                                     // per-layer counters (64B apart)
    __shared__ float cbuf[NB * HID];

    // ---- stage all x into LDS as f16 pairs (coalesced) ----
    for (int i = tid; i < NB * T_LEN; i += NT) {
        const int nn = i >> 10, t = i & (T_LEN - 1);
        const float2 v = *(const float2*)(x + ((size_t)(b0 + nn) * T_LEN + t) * 2);
        half2v p; p[0] = (_Float16)v.x; p[1] = (_Float16)v.y;
        xs[t * NB + nn] = __builtin_bit_cast(u32, p);
    }
    for (int i = tid; i < (int)(sizeof(ring) / 4); i += NT) ((u32*)ring)[i] = 0u;
    if (tid < 48) cnt[tid] = 0u;

    // ---- A fragments + bias (role-pair packed tiles), exp2-prescaled (r11 verbatim) ----
    const float* Wih = (l == 0) ? Wih0 : (l == 1) ? Wih1 : Wih2;
    const float* Whh = (l == 0) ? Whh0 : (l == 1) ? Whh1 : Whh2;
    const float* bih = (l == 0) ? bih0 : (l == 1) ? bih1 : bih2;
    const float* bhh = (l == 0) ? bhh0 : (l == 1) ? bhh1 : bhh2;

    half8 aprev[2], aself[2];
    f32x4 biasC[2];
#pragma unroll
    for (int tau = 0; tau < 2; ++tau) {
        const int   rho  = n & 1, uloc = n >> 1;
        const int   base = (tau == 0) ? (rho ? 32 : 0) : (rho ? 96 : 64);
        const int   R    = base + 8 * w + uloc;
        const float sc   = (tau == 1 && rho == 0) ? (2.0f * LOG2E) : LOG2E;
#pragma unroll
        for (int i2 = 0; i2 < 8; ++i2) {
            const int kk = kc * 8 + i2;
            aself[tau][i2] = (_Float16)(Whh[R * HID + kk] * sc);
            aprev[tau][i2] = (_Float16)(((l == 0) ? ((kk < 2) ? Wih[R * 2 + kk] : 0.0f)
                                                  : Wih[R * HID + kk]) * sc);
        }
#pragma unroll
        for (int r = 0; r < 4; ++r) {
            const int   rr    = r & 1, uD = 2 * kc + (r >> 1);
            const int   baseD = (tau == 0) ? (rr ? 32 : 0) : (rr ? 96 : 64);
            const int   RD    = baseD + 8 * w + uD;
            const float scD   = (tau == 1 && rr == 0) ? (2.0f * LOG2E) : LOG2E;
            biasC[tau][r] = (bih[RD] + bhh[RD]) * scD;
        }
    }

    // ---- ring offsets ----
    const int off_r0 = ((l == 0) ? 3 : (l - 1)) * SLOTB + n * ROWB + kc * 16;
    const int off_r1 = l * SLOTB + n * ROWB + kc * 16;
    const int off_w  = l * SLOTB + n * ROWB + (8 * w + 2 * kc) * 2;
    const int off_x  = 3 * SLOTB + lane * ROWB;
    const bool xf    = (wave == 0) && (lane < 16);

    u32* cs = &cnt[l * 16];
    u32* cp = &cnt[((l > 0) ? (l - 1) : 0) * 16];
    u32* cn = &cnt[((l < 2) ? (l + 1) : 0) * 16];

    float cc0 = 0.0f, cc1 = 0.0f;

    __syncthreads();
    if (xf) *(u32*)(ring + off_x) = xs[lane];   // slot0 x-row <- x(0)
    __syncthreads();

#define CELL(ai, af_, ag, ao, CC, HOUT)                                          \
    do {                                                                         \
        const float ei = FAST_EXP2(-(ai));                                       \
        const float ef = FAST_EXP2(-(af_));                                      \
        const float eg = FAST_EXP2(-(ag));                                       \
        const float eo = FAST_EXP2(-(ao));                                       \
        const float p1  = (1.0f + ei) * (1.0f + eg);                             \
        const float den = p1 * (1.0f + ef);                                      \
        const float tmn = (1.0f - eg) * (1.0f + ef);                             \
        float c_ = fmaf(CC, p1, tmn) * FAST_RCP(den);                            \
        c_ = fminf(fmaxf(c_, -20.0f), 20.0f);                                    \
        CC = c_;                                                                 \
        const float ec = FAST_EXP2(-2.0f * LOG2E * c_);                          \
        HOUT = (1.0f - ec) * FAST_RCP((1.0f + eo) * (1.0f + ec));                \
    } while (0)

    for (int tb = 0; tb < T_LEN; tb += NSLOT) {
#pragma unroll
        for (int s = 0; s < NSLOT; ++s) {
            const int t = tb + s;                         // this wave's own timestep
            if (t > 0)                 waitc(cs, 4u * (u32)t);        // own h(t-1) done
            if (l > 0)                 waitc(cp, 4u * (u32)(t + 1));  // h_{l-1}(t) ready
            if (l < 2 && t >= NSLOT)   waitc(cn, 4u * (u32)(t - 7));  // ring backpressure

            u32 xw = 0;
            if (xf) {
                const int tn = (t + 1 < T_LEN) ? (t + 1) : (T_LEN - 1);
                xw = xs[tn * NB + lane];
            }
            const half8 bf0 = __builtin_bit_cast(half8,
                *(const u32x4*)(ring + s * SLOT_ALL + off_r0));
            const half8 bf1 = __builtin_bit_cast(half8,
                *(const u32x4*)(ring + ((s + 7) & 7) * SLOT_ALL + off_r1));

            f32x4 ac0 = MFMA(aprev[0], bf0, biasC[0]);
            f32x4 ac1 = MFMA(aprev[1], bf0, biasC[1]);
            ac0 = MFMA(aself[0], bf1, ac0);
            ac1 = MFMA(aself[1], bf1, ac1);

            float h0, h1;
            CELL(ac0[0], ac0[1], ac1[0], ac1[1], cc0, h0);
            CELL(ac0[2], ac0[3], ac1[2], ac1[3], cc1, h1);

            *(u32*)(ring + s * SLOT_ALL + off_w) = PKRTZ(h0, h1);
            if (xf) *(u32*)(ring + ((s + 1) & 7) * SLOT_ALL + off_x) = xw;

            if (lane == 0)
                __hip_atomic_fetch_add(cs, 1u, __ATOMIC_RELEASE,
                                       __HIP_MEMORY_SCOPE_WORKGROUP);
        }
    }
#undef CELL

    // ---- final c3 of layer 2 -> LDS ----
    if (l == 2) {
        cbuf[n * HID + 8 * w + 2 * kc + 0] = cc0;
        cbuf[n * HID + 8 * w + 2 * kc + 1] = cc1;
    }
    __syncthreads();

    // ---- projection: mean / log_var ----
    if (tid < NB * 2 * LDIM) {
        const int  nn = tid >> 5;
        const int  o  = tid & 31;
        const bool is_mean = (o < LDIM);
        const int  jo = o & (LDIM - 1);
        const float* W  = is_mean ? Wm : Wlv;
        float acc = is_mean ? bm[jo] : blv[jo];
#pragma unroll
        for (int k = 0; k < HID; ++k) acc = fmaf(W[jo * HID + k], cbuf[nn * HID + k], acc);
        out[(is_mean ? 0 : (size_t)BATCH * LDIM) + (size_t)(b0 + nn) * LDIM + jo] = acc;
    }
}

extern "C" void kernel_launch(void* const* d_in, const int* in_sizes, int n_in,
                              void* d_out, int out_size, void* d_ws, size_t ws_size,
                              hipStream_t stream) {
    const float* x    = (const float*)d_in[0];
    const float* Wih0 = (const float*)d_in[1];
    const float* Whh0 = (const float*)d_in[2];
    const float* bih0 = (const float*)d_in[3];
    const float* bhh0 = (const float*)d_in[4];
    const float* Wih1 = (const float*)d_in[5];
    const float* Whh1 = (const float*)d_in[6];
    const float* bih1 = (const float*)d_in[7];
    const float* bhh1 = (const float*)d_in[8];
    const float* Wih2 = (const float*)d_in[9];
    const float* Whh2 = (const float*)d_in[10];
    const float* bih2 = (const float*)d_in[11];
    const float* bhh2 = (const float*)d_in[12];
    const float* Wm   = (const float*)d_in[13];
    const float* bm   = (const float*)d_in[14];
    const float* Wlv  = (const float*)d_in[15];
    const float* blv  = (const float*)d_in[16];
    float* out = (float*)d_out;

    lstm_encoder_kernel<<<dim3(BATCH / NB), dim3(NT), 0, stream>>>(
        x, Wih0, Whh0, bih0, bhh0, Wih1, Whh1, bih1, bhh1,
        Wih2, Whh2, bih2, bhh2, Wm, bm, Wlv, blv, out);
}

// Round 14
// 437.926 us; speedup vs baseline: 2.1885x; 1.1197x over previous
//
#include <hip/hip_runtime.h>

#define T_LEN 1024
#define HID   32
#define LDIM  16
#define BATCH 512
#define NB    8              // batch elems per block (B columns duplicated x2)
#define NT    768            // 12 waves: 3 layers x 4 unit-groups
#define ROWB  80             // bytes per batch-row (64 data + 16 pad)
#define SLOTB (8 * ROWB)     // 8 batch-rows = 640 B
#define SLOT_ALL (4 * SLOTB) // {h0,h1,h2,x} per time-slot = 2560 B
#define NSLOT 8              // h ring depth (t mod 8)
#define LOG2E 1.44269504f

typedef _Float16 half8  __attribute__((ext_vector_type(8)));
typedef _Float16 half2v __attribute__((ext_vector_type(2)));
typedef float    f32x4  __attribute__((ext_vector_type(4)));
typedef unsigned u32;
typedef unsigned u32x4  __attribute__((ext_vector_type(4)));

#if defined(__has_builtin)
#if __has_builtin(__builtin_amdgcn_rcpf)
#define FAST_RCP(x) __builtin_amdgcn_rcpf(x)
#endif
#if __has_builtin(__builtin_amdgcn_exp2f)
#define FAST_EXP2(x) __builtin_amdgcn_exp2f(x)
#endif
#endif
#ifndef FAST_RCP
#define FAST_RCP(x) (1.0f / (x))
#endif
#ifndef FAST_EXP2
#define FAST_EXP2(x) __expf(0.69314718f * (x))
#endif

#define MFMA(a, b, c) __builtin_amdgcn_mfma_f32_16x16x32_f16((a), (b), (c), 0, 0, 0)

// acquire-load spin on an LDS counter (wave-uniform address & condition)
__device__ __forceinline__ void waitc(const u32* p, u32 need) {
    while (__hip_atomic_load(p, __ATOMIC_ACQUIRE, __HIP_MEMORY_SCOPE_WORKGROUP) < need)
        __builtin_amdgcn_s_sleep(1);
}

__global__ __launch_bounds__(NT, 1)
void lstm_encoder_kernel(const float* __restrict__ x,
                         const float* __restrict__ Wih0, const float* __restrict__ Whh0,
                         const float* __restrict__ bih0, const float* __restrict__ bhh0,
                         const float* __restrict__ Wih1, const float* __restrict__ Whh1,
                         const float* __restrict__ bih1, const float* __restrict__ bhh1,
                         const float* __restrict__ Wih2, const float* __restrict__ Whh2,
                         const float* __restrict__ bih2, const float* __restrict__ bhh2,
                         const float* __restrict__ Wm,  const float* __restrict__ bm,
                         const float* __restrict__ Wlv, const float* __restrict__ blv,
                         float* __restrict__ out)
{
    const int b0   = blockIdx.x * NB;
    const int tid  = threadIdx.x;
    const int lane = tid & 63;
    const int wave = tid >> 6;        // 0..11
    const int l    = wave >> 2;       // layer 0..2
    const int w    = wave & 3;        // unit-group: units 8w..8w+7
    const int n    = lane & 15;       // B/D column; batch = n&7 (cols duplicated)
    const int kc   = lane >> 4;       // k-chunk / D row-quad
    const int nb   = n & 7;           // batch row
    const int hi   = n >> 3;          // which of the lane-pair's 2 cells this lane owns
    const int unit = 8 * w + 2 * kc + hi;

    __shared__ u32 xs[T_LEN * NB];                              // 32 KB packed f16 x [t][nb]
    __shared__ __align__(16) unsigned char ring[NSLOT * SLOT_ALL];  // 20 KB h/x ring
    __shared__ u32 cnt[48];                                     // per-layer counters (64B apart)
    __shared__ float cbuf[NB * HID];

    // ---- stage all x into LDS as f16 pairs (coalesced) ----
    for (int i = tid; i < NB * T_LEN; i += NT) {
        const int nn = i >> 10, t = i & (T_LEN - 1);
        const float2 v = *(const float2*)(x + ((size_t)(b0 + nn) * T_LEN + t) * 2);
        half2v p; p[0] = (_Float16)v.x; p[1] = (_Float16)v.y;
        xs[t * NB + nn] = __builtin_bit_cast(u32, p);
    }
    for (int i = tid; i < (int)(sizeof(ring) / 4); i += NT) ((u32*)ring)[i] = 0u;
    if (tid < 48) cnt[tid] = 0u;

    // ---- A fragments + bias (role-pair packed tiles), exp2-prescaled (r11/r13 verbatim) ----
    const float* Wih = (l == 0) ? Wih0 : (l == 1) ? Wih1 : Wih2;
    const float* Whh = (l == 0) ? Whh0 : (l == 1) ? Whh1 : Whh2;
    const float* bih = (l == 0) ? bih0 : (l == 1) ? bih1 : bih2;
    const float* bhh = (l == 0) ? bhh0 : (l == 1) ? bhh1 : bhh2;

    half8 aprev[2], aself[2];
    f32x4 biasC[2];
#pragma unroll
    for (int tau = 0; tau < 2; ++tau) {
        const int   rho  = n & 1, uloc = n >> 1;
        const int   base = (tau == 0) ? (rho ? 32 : 0) : (rho ? 96 : 64);
        const int   R    = base + 8 * w + uloc;
        const float sc   = (tau == 1 && rho == 0) ? (2.0f * LOG2E) : LOG2E;
#pragma unroll
        for (int i2 = 0; i2 < 8; ++i2) {
            const int kk = kc * 8 + i2;
            aself[tau][i2] = (_Float16)(Whh[R * HID + kk] * sc);
            aprev[tau][i2] = (_Float16)(((l == 0) ? ((kk < 2) ? Wih[R * 2 + kk] : 0.0f)
                                                  : Wih[R * HID + kk]) * sc);
        }
#pragma unroll
        for (int r = 0; r < 4; ++r) {
            const int   rr    = r & 1, uD = 2 * kc + (r >> 1);
            const int   baseD = (tau == 0) ? (rr ? 32 : 0) : (rr ? 96 : 64);
            const int   RD    = baseD + 8 * w + uD;
            const float scD   = (tau == 1 && rr == 0) ? (2.0f * LOG2E) : LOG2E;
            biasC[tau][r] = (bih[RD] + bhh[RD]) * scD;
        }
    }

    // ---- ring offsets (batch-row = n&7; B cols n / n+8 read the same row) ----
    const int off_r0 = ((l == 0) ? 3 : (l - 1)) * SLOTB + nb * ROWB + kc * 16;
    const int off_r1 = l * SLOTB + nb * ROWB + kc * 16;
    const int off_w  = l * SLOTB + nb * ROWB + unit * 2;
    const int off_x  = 3 * SLOTB + lane * ROWB;   // lanes < 8
    const bool xf    = (wave == 0) && (lane < NB);

    u32* cs = &cnt[l * 16];
    u32* cp = &cnt[((l > 0) ? (l - 1) : 0) * 16];
    u32* cn = &cnt[((l < 2) ? (l + 1) : 0) * 16];

    float cc = 0.0f;   // this lane's single cell (unit, batch nb)

    __syncthreads();
    if (xf) *(u32*)(ring + off_x) = xs[lane];   // slot0 x-row <- x(0)
    __syncthreads();

    for (int tb = 0; tb < T_LEN; tb += NSLOT) {
#pragma unroll
        for (int s = 0; s < NSLOT; ++s) {
            const int t = tb + s;
            if (t > 0)                 waitc(cs, 4u * (u32)t);        // own h(t-1) done
            if (l > 0)                 waitc(cp, 4u * (u32)(t + 1));  // h_{l-1}(t) ready
            if (l < 2 && t >= NSLOT)   waitc(cn, 4u * (u32)(t - 7));  // ring backpressure

            u32 xw = 0;
            if (xf) {
                const int tn = (t + 1 < T_LEN) ? (t + 1) : (T_LEN - 1);
                xw = xs[tn * NB + lane];
            }
            const half8 bf0 = __builtin_bit_cast(half8,
                *(const u32x4*)(ring + s * SLOT_ALL + off_r0));
            const half8 bf1 = __builtin_bit_cast(half8,
                *(const u32x4*)(ring + ((s + 7) & 7) * SLOT_ALL + off_r1));

            f32x4 ac0 = MFMA(aprev[0], bf0, biasC[0]);
            f32x4 ac1 = MFMA(aprev[1], bf0, biasC[1]);
            ac0 = MFMA(aself[0], bf1, ac0);
            ac1 = MFMA(aself[1], bf1, ac1);

            // this lane's cell: hi selects which of the duplicated pair it owns
            const float ai  = hi ? ac0[2] : ac0[0];
            const float af_ = hi ? ac0[3] : ac0[1];
            const float ag  = hi ? ac1[2] : ac1[0];
            const float ao  = hi ? ac1[3] : ac1[1];

            const float ei = FAST_EXP2(-ai);
            const float ef = FAST_EXP2(-af_);
            const float eg = FAST_EXP2(-ag);
            const float eo = FAST_EXP2(-ao);
            const float p1  = (1.0f + ei) * (1.0f + eg);
            const float den = p1 * (1.0f + ef);
            const float tmn = (1.0f - eg) * (1.0f + ef);
            float c_ = fmaf(cc, p1, tmn) * FAST_RCP(den);
            c_ = fminf(fmaxf(c_, -20.0f), 20.0f);
            cc = c_;
            const float ec = FAST_EXP2(-2.0f * LOG2E * c_);
            const float hv = (1.0f - ec) * FAST_RCP((1.0f + eo) * (1.0f + ec));  // o*tanh(c)

            *(_Float16*)(ring + s * SLOT_ALL + off_w) = (_Float16)hv;
            if (xf) *(u32*)(ring + ((s + 1) & 7) * SLOT_ALL + off_x) = xw;

            if (lane == 0)
                __hip_atomic_fetch_add(cs, 1u, __ATOMIC_RELEASE,
                                       __HIP_MEMORY_SCOPE_WORKGROUP);
        }
    }

    // ---- final c3 of layer 2 -> LDS ----
    if (l == 2) cbuf[nb * HID + unit] = cc;
    __syncthreads();

    // ---- projection: mean / log_var ----
    if (tid < NB * 2 * LDIM) {
        const int  nn = tid >> 5;
        const int  o  = tid & 31;
        const bool is_mean = (o < LDIM);
        const int  jo = o & (LDIM - 1);
        const float* W  = is_mean ? Wm : Wlv;
        float acc = is_mean ? bm[jo] : blv[jo];
#pragma unroll
        for (int k = 0; k < HID; ++k) acc = fmaf(W[jo * HID + k], cbuf[nn * HID + k], acc);
        out[(is_mean ? 0 : (size_t)BATCH * LDIM) + (size_t)(b0 + nn) * LDIM + jo] = acc;
    }
}

extern "C" void kernel_launch(void* const* d_in, const int* in_sizes, int n_in,
                              void* d_out, int out_size, void* d_ws, size_t ws_size,
                              hipStream_t stream) {
    const float* x    = (const float*)d_in[0];
    const float* Wih0 = (const float*)d_in[1];
    const float* Whh0 = (const float*)d_in[2];
    const float* bih0 = (const float*)d_in[3];
    const float* bhh0 = (const float*)d_in[4];
    const float* Wih1 = (const float*)d_in[5];
    const float* Whh1 = (const float*)d_in[6];
    const float* bih1 = (const float*)d_in[7];
    const float* bhh1 = (const float*)d_in[8];
    const float* Wih2 = (const float*)d_in[9];
    const float* Whh2 = (const float*)d_in[10];
    const float* bih2 = (const float*)d_in[11];
    const float* bhh2 = (const float*)d_in[12];
    const float* Wm   = (const float*)d_in[13];
    const float* bm   = (const float*)d_in[14];
    const float* Wlv  = (const float*)d_in[15];
    const float* blv  = (const float*)d_in[16];
    float* out = (float*)d_out;

    lstm_encoder_kernel<<<dim3(BATCH / NB), dim3(NT), 0, stream>>>(
        x, Wih0, Whh0, bih0, bhh0, Wih1, Whh1, bih1, bhh1,
        Wih2, Whh2, bih2, bhh2, Wm, bm, Wlv, blv, out);
}